// Round 6
// baseline (1132.738 us; speedup 1.0000x reference)
//
#include <hip/hip_runtime.h>
#include <hip/hip_bf16.h>

typedef __attribute__((ext_vector_type(4))) float  f4;
typedef __attribute__((ext_vector_type(8))) short  s8;
typedef __attribute__((ext_vector_type(4))) short  s4;

#define MFMA16(A,B,C) __builtin_amdgcn_mfma_f32_16x16x32_bf16((A),(B),(C),0,0,0)

// Native cast -> compiler emits v_cvt_pk_bf16_f32 for pairs (RNE).
__device__ __forceinline__ short f2bf(float f) {
  __hip_bfloat16 h = __float2bfloat16(f);
  return __builtin_bit_cast(short, h);
}

__device__ __forceinline__ f4 f4zero() { f4 z; z[0]=0.f; z[1]=0.f; z[2]=0.f; z[3]=0.f; return z; }

// Zero-cost fence: stops IR + MIR code motion across the LDS write->read handoff.
// DS pipe is in-order per wave, so no hardware wait is required for same-wave RAW.
__device__ __forceinline__ void wave_fence() {
  __builtin_amdgcn_wave_barrier();
  __builtin_amdgcn_sched_barrier(0);
}

// ---------------- prep: weight bf16 conversion + relative-position bias ----------------
__global__ __launch_bounds__(256) void prep_kernel(
    const float* __restrict__ qkv_w, const float* __restrict__ proj_w,
    const float* __restrict__ table,
    short* __restrict__ wqkv, short* __restrict__ wproj, float* __restrict__ biasf)
{
  int idx = blockIdx.x * 256 + threadIdx.x;
  if (idx < 196608) {
    wqkv[idx] = f2bf(qkv_w[idx]);
  } else if (idx < 262144) {
    int t = idx - 196608;
    wproj[t] = f2bf(proj_w[t]);
  } else {
    int t = idx - 262144;                 // [0, 32768): h*4096 + i*64 + j
    int h = t >> 12, i = (t >> 6) & 63, j = t & 63;
    int ridx = ((i >> 3) - (j >> 3) + 7) * 15 + ((i & 7) - (j & 7) + 7);
    biasf[t] = table[ridx * 8 + h];
  }
}

// ---------------- fused window attention ----------------
// Per-wave LDS areas only (no cooperative staging -> no intra-round barriers).
#define LDQ 40    // Q / K rows (32 data + 8 pad), shorts
#define LDV 72    // Vt rows (64 data + 8 pad)
#define LDP 72    // P rows
#define LDO 264   // Olds rows (256 data + 8 pad)
#define WAVE_LDS 14848   // bytes: Qs 5120 + Ks 5120 + Vt 4608

__global__ __launch_bounds__(256, 2) void fused_kernel(
    const float* __restrict__ x, const float* __restrict__ mask,
    const float* __restrict__ qkv_b, const float* __restrict__ proj_b,
    const short* __restrict__ wqkv, const short* __restrict__ wproj,
    const float* __restrict__ biasf, float* __restrict__ out)
{
  __shared__ __align__(16) char smem[59392];
  const int tid  = threadIdx.x;
  const int lane = tid & 63;
  const int wv   = tid >> 6;          // wave 0..3
  const int m16  = lane & 15;
  const int quad = lane >> 4;
  const int b    = blockIdx.x;
  const float* xg = x + (size_t)b * 16384;

  short* Qs = (short*)(smem + wv * WAVE_LDS);               // [64][40]
  short* Ks = Qs + 2560;                                    // [64][40]
  short* Vt = Ks + 2560;                                    // [32][72]
  short* Ps = Qs;                                           // [64][72] overlay on Qs+Ks

  s4 opack[2][2][4];                                        // O in bf16 [round][td][ti]
  const float scale = 0.17677669529663687f;                 // 32^-0.5

  for (int rnd = 0; rnd < 2; ++rnd) {
    const int h = wv + rnd * 4;

    // ---- qkv GEMM for head h: fragments straight from global fp32, cvt in-register ----
    f4 acc[3][2][4];
    #pragma unroll
    for (int s = 0; s < 3; ++s)
      #pragma unroll
      for (int tn = 0; tn < 2; ++tn)
        #pragma unroll
        for (int ti = 0; ti < 4; ++ti) acc[s][tn][ti] = f4zero();

    #pragma unroll
    for (int ks = 0; ks < 8; ++ks) {
      s8 af[4];
      #pragma unroll
      for (int ti = 0; ti < 4; ++ti) {
        const float* sp = xg + (m16 + 16*ti) * 256 + ks*32 + quad*8;
        f4 a = *(const f4*)sp;
        f4 c = *(const f4*)(sp + 4);
        s8 v;
        v[0]=f2bf(a[0]); v[1]=f2bf(a[1]); v[2]=f2bf(a[2]); v[3]=f2bf(a[3]);
        v[4]=f2bf(c[0]); v[5]=f2bf(c[1]); v[6]=f2bf(c[2]); v[7]=f2bf(c[3]);
        af[ti] = v;
      }
      #pragma unroll
      for (int s = 0; s < 3; ++s)
        #pragma unroll
        for (int tn = 0; tn < 2; ++tn) {
          const s8 bf = *(const s8*)&wqkv[(size_t)(s*256 + h*32 + tn*16 + m16) * 256 + ks*32 + quad*8];
          #pragma unroll
          for (int ti = 0; ti < 4; ++ti)
            // s<2 swapped (W as A): D[d in quad*4+p][token in m16] -> d-contiguous LDS writes.
            // s=2 unswapped: D[token in quad*4+p][d in m16] -> Vt token-contiguous writes.
            acc[s][tn][ti] = (s < 2) ? MFMA16(bf, af[ti], acc[s][tn][ti])
                                     : MFMA16(af[ti], bf, acc[s][tn][ti]);
        }
    }

    // ---- epilogue: +bias, q*=scale; all LDS writes are b64 ----
    #pragma unroll
    for (int tn = 0; tn < 2; ++tn) {
      f4 bq = *(const f4*)&qkv_b[0*256 + h*32 + tn*16 + quad*4];
      f4 bk = *(const f4*)&qkv_b[1*256 + h*32 + tn*16 + quad*4];
      float bv = qkv_b[2*256 + h*32 + tn*16 + m16];
      #pragma unroll
      for (int ti = 0; ti < 4; ++ti) {
        f4 vq = (acc[0][tn][ti] + bq) * scale;
        f4 vk =  acc[1][tn][ti] + bk;
        s4 q4; q4[0]=f2bf(vq[0]); q4[1]=f2bf(vq[1]); q4[2]=f2bf(vq[2]); q4[3]=f2bf(vq[3]);
        s4 k4; k4[0]=f2bf(vk[0]); k4[1]=f2bf(vk[1]); k4[2]=f2bf(vk[2]); k4[3]=f2bf(vk[3]);
        *(s4*)&Qs[(ti*16 + m16)*LDQ + tn*16 + quad*4] = q4;   // [tok][d]
        *(s4*)&Ks[(ti*16 + m16)*LDQ + tn*16 + quad*4] = k4;   // [tok][d]
        f4 vv = acc[2][tn][ti] + bv;
        s4 v4; v4[0]=f2bf(vv[0]); v4[1]=f2bf(vv[1]); v4[2]=f2bf(vv[2]); v4[3]=f2bf(vv[3]);
        *(s4*)&Vt[(tn*16 + m16)*LDV + ti*16 + quad*4] = v4;   // [d][tok]
      }
    }
    wave_fence();

    // ---- S^T = K * Q^T (NT trick: both frags row-major [tok][d]) ----
    s8 qf[4], kf[4];
    #pragma unroll
    for (int t = 0; t < 4; ++t) {
      qf[t] = *(const s8*)&Qs[(m16 + 16*t) * LDQ + quad*8];
      kf[t] = *(const s8*)&Ks[(m16 + 16*t) * LDQ + quad*8];
    }
    f4 st[4][4];   // st[tjr][tic][p] = S[i=tic*16+m16][j=tjr*16+quad*4+p]
    #pragma unroll
    for (int tjr = 0; tjr < 4; ++tjr)
      #pragma unroll
      for (int tic = 0; tic < 4; ++tic)
        st[tjr][tic] = MFMA16(kf[tjr], qf[tic], f4zero());

    // bias + mask (float4 loads, j-contiguous thanks to S^T layout)
    const float* maskw = mask + (size_t)(b & 63) * 4096;
    #pragma unroll
    for (int tic = 0; tic < 4; ++tic) {
      int i = tic*16 + m16;
      #pragma unroll
      for (int tjr = 0; tjr < 4; ++tjr) {
        int j0 = tjr*16 + quad*4;
        f4 bb = *(const f4*)&biasf[(h*64 + i)*64 + j0];
        f4 mm = *(const f4*)&maskw[i*64 + j0];
        st[tjr][tic] += bb + mm;
      }
    }

    // ---- softmax over j (16 local values + xor16 + xor32) ----
    float linv[4];
    #pragma unroll
    for (int tic = 0; tic < 4; ++tic) {
      float mx = -1e30f;
      #pragma unroll
      for (int tjr = 0; tjr < 4; ++tjr)
        #pragma unroll
        for (int p = 0; p < 4; ++p) mx = fmaxf(mx, st[tjr][tic][p]);
      mx = fmaxf(mx, __shfl_xor(mx, 16, 64));
      mx = fmaxf(mx, __shfl_xor(mx, 32, 64));
      float sum = 0.f;
      #pragma unroll
      for (int tjr = 0; tjr < 4; ++tjr)
        #pragma unroll
        for (int p = 0; p < 4; ++p) {
          float e = exp2f((st[tjr][tic][p] - mx) * 1.4426950408889634f);
          st[tjr][tic][p] = e;
          sum += e;
        }
      sum += __shfl_xor(sum, 16, 64);
      sum += __shfl_xor(sum, 32, 64);
      linv[tic] = 1.f / sum;
    }

    // ---- write P (unnormalized exp) to LDS, b64-packed (overlay on Qs/Ks) ----
    #pragma unroll
    for (int tic = 0; tic < 4; ++tic) {
      int i = tic*16 + m16;
      #pragma unroll
      for (int tjr = 0; tjr < 4; ++tjr) {
        int j0 = tjr*16 + quad*4;
        s4 pv;
        pv[0]=f2bf(st[tjr][tic][0]); pv[1]=f2bf(st[tjr][tic][1]);
        pv[2]=f2bf(st[tjr][tic][2]); pv[3]=f2bf(st[tjr][tic][3]);
        *(s4*)&Ps[i*LDP + j0] = pv;
      }
    }
    wave_fence();

    // ---- O^T = Vt * P^T ----
    s8 vtf[2][2], pf[4][2];
    #pragma unroll
    for (int td = 0; td < 2; ++td)
      #pragma unroll
      for (int kk = 0; kk < 2; ++kk)
        vtf[td][kk] = *(const s8*)&Vt[(m16 + 16*td)*LDV + kk*32 + quad*8];
    #pragma unroll
    for (int ti = 0; ti < 4; ++ti)
      #pragma unroll
      for (int kk = 0; kk < 2; ++kk)
        pf[ti][kk] = *(const s8*)&Ps[(m16 + 16*ti)*LDP + kk*32 + quad*8];
    #pragma unroll
    for (int td = 0; td < 2; ++td)
      #pragma unroll
      for (int ti = 0; ti < 4; ++ti) {
        f4 o = MFMA16(vtf[td][0], pf[ti][0], f4zero());
        o = MFMA16(vtf[td][1], pf[ti][1], o);
        float li = linv[ti];
        s4 ov;
        ov[0]=f2bf(o[0]*li); ov[1]=f2bf(o[1]*li);
        ov[2]=f2bf(o[2]*li); ov[3]=f2bf(o[3]*li);
        opack[rnd][td][ti] = ov;                 // bf16-packed: halves live regs
      }
  } // rounds

  // ---- gather all heads' O into shared Olds [64][256] bf16 ----
  __syncthreads();                       // Olds overlays per-wave areas
  short* Olds = (short*)smem;
  #pragma unroll
  for (int rnd = 0; rnd < 2; ++rnd) {
    int h = wv + rnd*4;
    #pragma unroll
    for (int td = 0; td < 2; ++td)
      #pragma unroll
      for (int ti = 0; ti < 4; ++ti) {
        int i  = m16 + 16*ti;
        int d0 = h*32 + td*16 + quad*4;
        *(s4*)&Olds[i*LDO + d0] = opack[rnd][td][ti];
      }
  }
  __syncthreads();

  // ---- proj GEMM: out[64][256] = Olds * projW^T + proj_b (swapped -> f4 stores) ----
  f4 pacc[4][4];
  #pragma unroll
  for (int tn = 0; tn < 4; ++tn)
    #pragma unroll
    for (int ti = 0; ti < 4; ++ti) pacc[tn][ti] = f4zero();

  #pragma unroll
  for (int ks = 0; ks < 8; ++ks) {
    s8 af[4];
    #pragma unroll
    for (int ti = 0; ti < 4; ++ti)
      af[ti] = *(const s8*)&Olds[(m16 + 16*ti)*LDO + ks*32 + quad*8];
    #pragma unroll
    for (int tn = 0; tn < 4; ++tn) {
      const s8 bf = *(const s8*)&wproj[(size_t)(wv*64 + tn*16 + m16)*256 + ks*32 + quad*8];
      #pragma unroll
      for (int ti = 0; ti < 4; ++ti)
        pacc[tn][ti] = MFMA16(bf, af[ti], pacc[tn][ti]);   // D[c in quad*4+p][tok in m16]
    }
  }

  float* outb = out + (size_t)b * 16384;
  #pragma unroll
  for (int tn = 0; tn < 4; ++tn) {
    int c0 = wv*64 + tn*16 + quad*4;
    f4 pb = *(const f4*)&proj_b[c0];
    #pragma unroll
    for (int ti = 0; ti < 4; ++ti) {
      int i = ti*16 + m16;
      f4 v = pacc[tn][ti] + pb;
      *(f4*)&outb[(size_t)i*256 + c0] = v;
    }
  }
}

extern "C" void kernel_launch(void* const* d_in, const int* in_sizes, int n_in,
                              void* d_out, int out_size, void* d_ws, size_t ws_size,
                              hipStream_t stream) {
  (void)in_sizes; (void)n_in; (void)out_size; (void)ws_size;
  const float* x      = (const float*)d_in[0];
  const float* mask   = (const float*)d_in[1];
  const float* qkv_w  = (const float*)d_in[2];
  const float* qkv_b  = (const float*)d_in[3];
  const float* proj_w = (const float*)d_in[4];
  const float* proj_b = (const float*)d_in[5];
  const float* table  = (const float*)d_in[6];
  // d_in[7] (rel_index) unused: index computed analytically (dtype-safe).
  float* out = (float*)d_out;

  char* ws = (char*)d_ws;
  short* wqkv  = (short*)ws;                // 196608 bf16 = 393216 B
  short* wproj = (short*)(ws + 393216);     //  65536 bf16 = 131072 B
  float* biasf = (float*)(ws + 524288);     //  32768 f32  = 131072 B  (total 640 KB)

  prep_kernel<<<1152, 256, 0, stream>>>(qkv_w, proj_w, table, wqkv, wproj, biasf);
  fused_kernel<<<4096, 256, 0, stream>>>(x, mask, qkv_b, proj_b, wqkv, wproj, biasf, out);
}

// Round 7
// 940.426 us; speedup vs baseline: 1.2045x; 1.2045x over previous
//
#include <hip/hip_runtime.h>
#include <hip/hip_bf16.h>

typedef __attribute__((ext_vector_type(4))) float  f4;
typedef __attribute__((ext_vector_type(8))) short  s8;
typedef __attribute__((ext_vector_type(4))) short  s4;

#define MFMA16(A,B,C) __builtin_amdgcn_mfma_f32_16x16x32_bf16((A),(B),(C),0,0,0)

// Native cast -> compiler emits v_cvt_pk_bf16_f32 for pairs (RNE).
__device__ __forceinline__ short f2bf(float f) {
  __hip_bfloat16 h = __float2bfloat16(f);
  return __builtin_bit_cast(short, h);
}

__device__ __forceinline__ f4 f4zero() { f4 z; z[0]=0.f; z[1]=0.f; z[2]=0.f; z[3]=0.f; return z; }

// Zero-cost fence: stops IR + MIR code motion across the LDS write->read handoff.
// DS pipe is in-order per wave, so no hardware wait is required for same-wave RAW.
__device__ __forceinline__ void wave_fence() {
  __builtin_amdgcn_wave_barrier();
  __builtin_amdgcn_sched_barrier(0);
}

// ---------------- prep: x/weight bf16 conversion + relative-position bias ----------------
// idx < nx8           : convert 8 elems of x (f32 -> bf16), vectorized 32B read / 16B write
// idx - nx8 < 196608  : wqkv
// idx - nx8 < 262144  : wproj
// else                : bias gather (analytic swin rel-index)
__global__ __launch_bounds__(256) void prep_kernel(
    const float* __restrict__ x, short* __restrict__ xbf, int nx8,
    const float* __restrict__ qkv_w, const float* __restrict__ proj_w,
    const float* __restrict__ table,
    short* __restrict__ wqkv, short* __restrict__ wproj, float* __restrict__ biasf)
{
  int idx = blockIdx.x * 256 + threadIdx.x;
  if (idx < nx8) {
    const f4* src = (const f4*)(x + (size_t)idx * 8);
    f4 a = src[0], c = src[1];
    s8 v;
    v[0]=f2bf(a[0]); v[1]=f2bf(a[1]); v[2]=f2bf(a[2]); v[3]=f2bf(a[3]);
    v[4]=f2bf(c[0]); v[5]=f2bf(c[1]); v[6]=f2bf(c[2]); v[7]=f2bf(c[3]);
    *(s8*)(xbf + (size_t)idx * 8) = v;
    return;
  }
  int t = idx - nx8;
  if (t < 196608) {
    wqkv[t] = f2bf(qkv_w[t]);
  } else if (t < 262144) {
    int u = t - 196608;
    wproj[u] = f2bf(proj_w[u]);
  } else {
    int u = t - 262144;                 // [0, 32768): h*4096 + i*64 + j
    int h = u >> 12, i = (u >> 6) & 63, j = u & 63;
    int ridx = ((i >> 3) - (j >> 3) + 7) * 15 + ((i & 7) - (j & 7) + 7);
    biasf[u] = table[ridx * 8 + h];
  }
}

// ---------------- fused window attention ----------------
// Per-wave LDS areas only (no cooperative staging -> no intra-round barriers).
#define LDQ 40    // Q / K rows (32 data + 8 pad), shorts
#define LDV 72    // Vt rows (64 data + 8 pad)
#define LDP 72    // P rows
#define LDO 264   // Olds rows (256 data + 8 pad)
#define WAVE_LDS 14848   // bytes: Qs 5120 + Ks 5120 + Vt 4608

// XB=1: x already bf16 in workspace (fragment loads are direct s8, zero cvt VALU).
// XB=0: fallback, x fp32 + in-register cvt (used only if workspace too small).
template<int XB>
__global__ __launch_bounds__(256, 2) void fused_kernel(
    const void* __restrict__ xv, const float* __restrict__ mask,
    const float* __restrict__ qkv_b, const float* __restrict__ proj_b,
    const short* __restrict__ wqkv, const short* __restrict__ wproj,
    const float* __restrict__ biasf, float* __restrict__ out)
{
  __shared__ __align__(16) char smem[59392];
  const int tid  = threadIdx.x;
  const int lane = tid & 63;
  const int wv   = tid >> 6;          // wave 0..3
  const int m16  = lane & 15;
  const int quad = lane >> 4;
  const int b    = blockIdx.x;

  short* Qs = (short*)(smem + wv * WAVE_LDS);               // [64][40]
  short* Ks = Qs + 2560;                                    // [64][40]
  short* Vt = Ks + 2560;                                    // [32][72]
  short* Ps = Qs;                                           // [64][72] overlay on Qs+Ks

  s4 opack[2][2][4];                                        // O in bf16 [round][td][ti]
  const float scale = 0.17677669529663687f;                 // 32^-0.5

  #pragma unroll            // MUST unroll: opack[rnd] needs compile-time index (no scratch)
  for (int rnd = 0; rnd < 2; ++rnd) {
    const int h = wv + rnd * 4;

    // ---- qkv GEMM for head h ----
    f4 acc[3][2][4];
    #pragma unroll
    for (int s = 0; s < 3; ++s)
      #pragma unroll
      for (int tn = 0; tn < 2; ++tn)
        #pragma unroll
        for (int ti = 0; ti < 4; ++ti) acc[s][tn][ti] = f4zero();

    #pragma unroll
    for (int ks = 0; ks < 8; ++ks) {
      s8 af[4];
      #pragma unroll
      for (int ti = 0; ti < 4; ++ti) {
        if constexpr (XB) {
          const short* xg = (const short*)xv + (size_t)b * 16384;
          af[ti] = *(const s8*)&xg[(m16 + 16*ti) * 256 + ks*32 + quad*8];
        } else {
          const float* xg = (const float*)xv + (size_t)b * 16384;
          const float* sp = xg + (m16 + 16*ti) * 256 + ks*32 + quad*8;
          f4 a = *(const f4*)sp;
          f4 c = *(const f4*)(sp + 4);
          s8 v;
          v[0]=f2bf(a[0]); v[1]=f2bf(a[1]); v[2]=f2bf(a[2]); v[3]=f2bf(a[3]);
          v[4]=f2bf(c[0]); v[5]=f2bf(c[1]); v[6]=f2bf(c[2]); v[7]=f2bf(c[3]);
          af[ti] = v;
        }
      }
      #pragma unroll
      for (int s = 0; s < 3; ++s)
        #pragma unroll
        for (int tn = 0; tn < 2; ++tn) {
          const s8 bf = *(const s8*)&wqkv[(size_t)(s*256 + h*32 + tn*16 + m16) * 256 + ks*32 + quad*8];
          #pragma unroll
          for (int ti = 0; ti < 4; ++ti)
            // s<2 swapped (W as A): D[d in quad*4+p][token in m16] -> d-contiguous LDS writes.
            // s=2 unswapped: D[token in quad*4+p][d in m16] -> Vt token-contiguous writes.
            acc[s][tn][ti] = (s < 2) ? MFMA16(bf, af[ti], acc[s][tn][ti])
                                     : MFMA16(af[ti], bf, acc[s][tn][ti]);
        }
    }

    // ---- epilogue: +bias, q*=scale; all LDS writes are b64 ----
    #pragma unroll
    for (int tn = 0; tn < 2; ++tn) {
      f4 bq = *(const f4*)&qkv_b[0*256 + h*32 + tn*16 + quad*4];
      f4 bk = *(const f4*)&qkv_b[1*256 + h*32 + tn*16 + quad*4];
      float bv = qkv_b[2*256 + h*32 + tn*16 + m16];
      #pragma unroll
      for (int ti = 0; ti < 4; ++ti) {
        f4 vq = (acc[0][tn][ti] + bq) * scale;
        f4 vk =  acc[1][tn][ti] + bk;
        s4 q4; q4[0]=f2bf(vq[0]); q4[1]=f2bf(vq[1]); q4[2]=f2bf(vq[2]); q4[3]=f2bf(vq[3]);
        s4 k4; k4[0]=f2bf(vk[0]); k4[1]=f2bf(vk[1]); k4[2]=f2bf(vk[2]); k4[3]=f2bf(vk[3]);
        *(s4*)&Qs[(ti*16 + m16)*LDQ + tn*16 + quad*4] = q4;   // [tok][d]
        *(s4*)&Ks[(ti*16 + m16)*LDQ + tn*16 + quad*4] = k4;   // [tok][d]
        f4 vv = acc[2][tn][ti] + bv;
        s4 v4; v4[0]=f2bf(vv[0]); v4[1]=f2bf(vv[1]); v4[2]=f2bf(vv[2]); v4[3]=f2bf(vv[3]);
        *(s4*)&Vt[(tn*16 + m16)*LDV + ti*16 + quad*4] = v4;   // [d][tok]
      }
    }
    wave_fence();

    // ---- S^T = K * Q^T (NT trick: both frags row-major [tok][d]) ----
    s8 qf[4], kf[4];
    #pragma unroll
    for (int t = 0; t < 4; ++t) {
      qf[t] = *(const s8*)&Qs[(m16 + 16*t) * LDQ + quad*8];
      kf[t] = *(const s8*)&Ks[(m16 + 16*t) * LDQ + quad*8];
    }
    f4 st[4][4];   // st[tjr][tic][p] = S[i=tic*16+m16][j=tjr*16+quad*4+p]
    #pragma unroll
    for (int tjr = 0; tjr < 4; ++tjr)
      #pragma unroll
      for (int tic = 0; tic < 4; ++tic)
        st[tjr][tic] = MFMA16(kf[tjr], qf[tic], f4zero());

    // bias + mask (float4 loads, j-contiguous thanks to S^T layout)
    const float* maskw = mask + (size_t)(b & 63) * 4096;
    #pragma unroll
    for (int tic = 0; tic < 4; ++tic) {
      int i = tic*16 + m16;
      #pragma unroll
      for (int tjr = 0; tjr < 4; ++tjr) {
        int j0 = tjr*16 + quad*4;
        f4 bb = *(const f4*)&biasf[(h*64 + i)*64 + j0];
        f4 mm = *(const f4*)&maskw[i*64 + j0];
        st[tjr][tic] += bb + mm;
      }
    }

    // ---- softmax over j (16 local values + xor16 + xor32) ----
    float linv[4];
    #pragma unroll
    for (int tic = 0; tic < 4; ++tic) {
      float mx = -1e30f;
      #pragma unroll
      for (int tjr = 0; tjr < 4; ++tjr)
        #pragma unroll
        for (int p = 0; p < 4; ++p) mx = fmaxf(mx, st[tjr][tic][p]);
      mx = fmaxf(mx, __shfl_xor(mx, 16, 64));
      mx = fmaxf(mx, __shfl_xor(mx, 32, 64));
      float sum = 0.f;
      #pragma unroll
      for (int tjr = 0; tjr < 4; ++tjr)
        #pragma unroll
        for (int p = 0; p < 4; ++p) {
          float e = exp2f((st[tjr][tic][p] - mx) * 1.4426950408889634f);
          st[tjr][tic][p] = e;
          sum += e;
        }
      sum += __shfl_xor(sum, 16, 64);
      sum += __shfl_xor(sum, 32, 64);
      linv[tic] = 1.f / sum;
    }

    // ---- write P (unnormalized exp) to LDS, b64-packed (overlay on Qs/Ks) ----
    #pragma unroll
    for (int tic = 0; tic < 4; ++tic) {
      int i = tic*16 + m16;
      #pragma unroll
      for (int tjr = 0; tjr < 4; ++tjr) {
        int j0 = tjr*16 + quad*4;
        s4 pv;
        pv[0]=f2bf(st[tjr][tic][0]); pv[1]=f2bf(st[tjr][tic][1]);
        pv[2]=f2bf(st[tjr][tic][2]); pv[3]=f2bf(st[tjr][tic][3]);
        *(s4*)&Ps[i*LDP + j0] = pv;
      }
    }
    wave_fence();

    // ---- O^T = Vt * P^T ----
    s8 vtf[2][2], pf[4][2];
    #pragma unroll
    for (int td = 0; td < 2; ++td)
      #pragma unroll
      for (int kk = 0; kk < 2; ++kk)
        vtf[td][kk] = *(const s8*)&Vt[(m16 + 16*td)*LDV + kk*32 + quad*8];
    #pragma unroll
    for (int ti = 0; ti < 4; ++ti)
      #pragma unroll
      for (int kk = 0; kk < 2; ++kk)
        pf[ti][kk] = *(const s8*)&Ps[(m16 + 16*ti)*LDP + kk*32 + quad*8];
    #pragma unroll
    for (int td = 0; td < 2; ++td)
      #pragma unroll
      for (int ti = 0; ti < 4; ++ti) {
        f4 o = MFMA16(vtf[td][0], pf[ti][0], f4zero());
        o = MFMA16(vtf[td][1], pf[ti][1], o);
        float li = linv[ti];
        s4 ov;
        ov[0]=f2bf(o[0]*li); ov[1]=f2bf(o[1]*li);
        ov[2]=f2bf(o[2]*li); ov[3]=f2bf(o[3]*li);
        opack[rnd][td][ti] = ov;                 // bf16-packed: halves live regs
      }
  } // rounds

  // ---- gather all heads' O into shared Olds [64][256] bf16 ----
  __syncthreads();                       // Olds overlays per-wave areas
  short* Olds = (short*)smem;
  #pragma unroll
  for (int rnd = 0; rnd < 2; ++rnd) {
    int h = wv + rnd*4;
    #pragma unroll
    for (int td = 0; td < 2; ++td)
      #pragma unroll
      for (int ti = 0; ti < 4; ++ti) {
        int i  = m16 + 16*ti;
        int d0 = h*32 + td*16 + quad*4;
        *(s4*)&Olds[i*LDO + d0] = opack[rnd][td][ti];
      }
  }
  __syncthreads();

  // ---- proj GEMM: out[64][256] = Olds * projW^T + proj_b (swapped -> f4 stores) ----
  f4 pacc[4][4];
  #pragma unroll
  for (int tn = 0; tn < 4; ++tn)
    #pragma unroll
    for (int ti = 0; ti < 4; ++ti) pacc[tn][ti] = f4zero();

  #pragma unroll
  for (int ks = 0; ks < 8; ++ks) {
    s8 af[4];
    #pragma unroll
    for (int ti = 0; ti < 4; ++ti)
      af[ti] = *(const s8*)&Olds[(m16 + 16*ti)*LDO + ks*32 + quad*8];
    #pragma unroll
    for (int tn = 0; tn < 4; ++tn) {
      const s8 bf = *(const s8*)&wproj[(size_t)(wv*64 + tn*16 + m16)*256 + ks*32 + quad*8];
      #pragma unroll
      for (int ti = 0; ti < 4; ++ti)
        pacc[tn][ti] = MFMA16(bf, af[ti], pacc[tn][ti]);   // D[c in quad*4+p][tok in m16]
    }
  }

  // ti-outer store order: each row's 4x64B chunks issue back-to-back (write combining)
  float* outb = out + (size_t)b * 16384;
  f4 pb[4];
  #pragma unroll
  for (int tn = 0; tn < 4; ++tn) pb[tn] = *(const f4*)&proj_b[wv*64 + tn*16 + quad*4];
  #pragma unroll
  for (int ti = 0; ti < 4; ++ti) {
    int i = ti*16 + m16;
    #pragma unroll
    for (int tn = 0; tn < 4; ++tn) {
      int c0 = wv*64 + tn*16 + quad*4;
      f4 v = pacc[tn][ti] + pb[tn];
      *(f4*)&outb[(size_t)i*256 + c0] = v;
    }
  }
}

extern "C" void kernel_launch(void* const* d_in, const int* in_sizes, int n_in,
                              void* d_out, int out_size, void* d_ws, size_t ws_size,
                              hipStream_t stream) {
  (void)in_sizes; (void)n_in; (void)out_size;
  const float* x      = (const float*)d_in[0];
  const float* mask   = (const float*)d_in[1];
  const float* qkv_w  = (const float*)d_in[2];
  const float* qkv_b  = (const float*)d_in[3];
  const float* proj_w = (const float*)d_in[4];
  const float* proj_b = (const float*)d_in[5];
  const float* table  = (const float*)d_in[6];
  // d_in[7] (rel_index) unused: index computed analytically (dtype-safe).
  float* out = (float*)d_out;

  const size_t XBF_BYTES = 134217728ull;     // 4096*64*256 bf16
  const size_t TAIL_BYTES = 655360ull;       // wqkv 384K + wproj 128K + biasf 128K
  char* ws = (char*)d_ws;

  if (ws_size >= XBF_BYTES + TAIL_BYTES) {
    short* xbf   = (short*)ws;
    short* wqkv  = (short*)(ws + XBF_BYTES);
    short* wproj = (short*)(ws + XBF_BYTES + 393216);
    float* biasf = (float*)(ws + XBF_BYTES + 524288);
    const int nx8 = 8388608;                 // 67.1M elems / 8 per thread
    prep_kernel<<<(nx8 + 294912) / 256, 256, 0, stream>>>(
        x, xbf, nx8, qkv_w, proj_w, table, wqkv, wproj, biasf);
    fused_kernel<1><<<4096, 256, 0, stream>>>(xbf, mask, qkv_b, proj_b, wqkv, wproj, biasf, out);
  } else {
    short* wqkv  = (short*)ws;
    short* wproj = (short*)(ws + 393216);
    float* biasf = (float*)(ws + 524288);
    prep_kernel<<<1152, 256, 0, stream>>>(
        x, (short*)nullptr, 0, qkv_w, proj_w, table, wqkv, wproj, biasf);
    fused_kernel<0><<<4096, 256, 0, stream>>>(x, mask, qkv_b, proj_b, wqkv, wproj, biasf, out);
  }
}